// Round 7
// baseline (43.305 us; speedup 1.0000x reference)
//
#include <hip/hip_runtime.h>

#define INV_SQRT2 0.70710678118654752f
#define SQRT3     1.73205080756887729f
#define INV_SQRT3 0.57735026918962576f
#define INV_SQRT6 0.40824829046386302f
#define PW1_000   0.70710678118654752f   // sqrt(0.5)
#define PW1_112   2.23606797749978970f   // sqrt(5)
#define K_P       0.70710678118654752f   // PW1_011*INV_SQRT3 = PW1_101*INV_SQRT3 = PW1_111*INV_SQRT6
#define K_V0      0.40824829046386302f   // PW1_110*INV_SQRT3
#define PW2       0.15309310892394863f   // sqrt(3/128)
#define NC        0.31622776601683794f   // 1/sqrt(10)
#define NC2       0.18257418583505537f   // 1/sqrt(30)

#define NA   512      // nodes per batch (fixed by problem)
#define NTH  1024     // threads per block
#define ECAP 12288    // LDS edge cache capacity (per-batch edges ~10.2K)

// one block per batch; all phases in one kernel, synced by __syncthreads()
__global__ void __launch_bounds__(1024) k_all(
    const int* __restrict__ nf, const float* __restrict__ rv,
    const int* __restrict__ esrc, const int* __restrict__ edst,
    const float* __restrict__ emb,
    const float* __restrict__ t1_000, const float* __restrict__ t1_011,
    const float* __restrict__ t1_101, const float* __restrict__ t1_110,
    const float* __restrict__ t1_111, const float* __restrict__ t1_112,
    const float* __restrict__ t2_0e, const float* __restrict__ t2_1e,
    const float* __restrict__ t2_1o, const float* __restrict__ t2_2e,
    float* __restrict__ out, int n, int E, int embsz)
{
    __shared__ float  rl[NA * 3];        // batch positions
    __shared__ float  el[304];           // emb table
    __shared__ int    ks[1026];          // coarse sampled sort keys
    __shared__ float4 hs[NA];            // Hsum per node
    __shared__ float4 ml[NA * 4];        // Mid per node (16 floats)
    __shared__ int    offs[NA + 1];      // local run bounds
    __shared__ int    ec[ECAP];          // local neighbor ids per edge
    __shared__ float  dd[6];             // weight-weight dots
    __shared__ int    gb[2];             // batch edge range [gbeg, gend)

    const int b = blockIdx.x, base = b * NA, t = threadIdx.x;
    const int stride = (E + 1023) >> 10;

    // ---- phase 0a: stage r, emb, coarse keys, weight dots --------------
    for (int i = t; i < NA * 3; i += NTH) rl[i] = rv[base * 3 + i];
    int esz = embsz < 304 ? embsz : 304;
    for (int i = t; i < esz; i += NTH) el[i] = emb[i];
    for (int i = t; i <= 1024; i += NTH) {
        int p = i * stride;
        ks[i] = (p >= E) ? n : ((edst[p] >= n) ? n : esrc[p]);
    }
    if (t < 64) {
        int l = t;
        auto wdot = [&](const float* a, const float* bb, int len) -> float {
            float v = (l < len) ? a[l] * bb[l] : 0.0f;
            for (int off = 32; off > 0; off >>= 1) v += __shfl_down(v, off);
            return v;
        };
        float d0 = wdot(t1_000, t2_0e, 64);
        float d1 = wdot(t1_110, t2_0e, 64);
        float d2 = wdot(t1_011, t2_1e, 24);
        float d3 = wdot(t1_101, t2_1e, 24);
        float d4 = wdot(t1_111, t2_1o, 24);
        float d5 = wdot(t1_112, t2_2e, 16);
        if (l == 0) { dd[0]=d0; dd[1]=d1; dd[2]=d2; dd[3]=d3; dd[4]=d4; dd[5]=d5; }
    }
    __syncthreads();

    // ---- phase 0b: batch edge-range via 2-level lower_bound ------------
    if (t < 2) {
        int target = base + t * NA;
        int lo = 0, hi = 1025;                       // coarse over ks
        while (lo < hi) { int m = (lo + hi) >> 1; if (ks[m] < target) lo = m + 1; else hi = m; }
        int glo = (lo == 0) ? 0 : (lo - 1) * stride;
        int ghi = lo * stride; if (ghi > E) ghi = E;
        while (glo < ghi) {                          // refine in global
            int m = (glo + ghi) >> 1;
            int d = edst[m];
            int k = (d >= n) ? n : esrc[m];
            if (k < target) glo = m + 1; else ghi = m;
        }
        gb[t] = glo;
    }
    __syncthreads();
    const int gbeg = gb[0];
    const int nE   = gb[1] - gb[0];

    // ---- phase 0c: boundary scan -> offs, edge cache -> ec -------------
    if (nE == 0) { for (int i = t; i <= NA; i += NTH) offs[i] = 0; }
    for (int i = t; i < nE; i += NTH) {
        int j = edst[gbeg + i] - base;               // local neighbor id
        if (i < ECAP) ec[i] = j;
        int s0 = esrc[gbeg + i] - base;
        int s1 = (i + 1 < nE) ? (esrc[gbeg + i + 1] - base) : NA;
        if (i == 0) for (int v = 0; v <= s0; ++v) offs[v] = 0;
        for (int v = s0 + 1; v <= s1; ++v) offs[v] = i + 1;
    }
    __syncthreads();

    // ---- phase H: Hsum[v] (2 lanes/node) --------------------------------
    {
        int v = t >> 1, ln = t & 1;
        int lo = offs[v], hi = offs[v + 1];
        float sx = 0.f, sy = 0.f, sz = 0.f;
        for (int p = lo + ln; p < hi; p += 2) {
            int j = (p < ECAP) ? ec[p] : (edst[gbeg + p] - base);
            sx += rl[j*3+0]; sy += rl[j*3+1]; sz += rl[j*3+2];
        }
        sx += __shfl_xor(sx, 1, 2);
        sy += __shfl_xor(sy, 1, 2);
        sz += __shfl_xor(sz, 1, 2);
        if (ln == 0) {
            float cnt = (float)(hi - lo);
            float rx = rl[v*3+0], ry = rl[v*3+1], rz = rl[v*3+2];
            int i0 = nf[(base+v)*3+0], i1 = nf[(base+v)*3+1], i2 = nf[(base+v)*3+2];
            float ex = el[i0*3+0] + el[i1*3+0] + el[i2*3+0];
            float ey = el[i0*3+1] + el[i1*3+1] + el[i2*3+1];
            float ez = el[i0*3+2] + el[i1*3+2] + el[i2*3+2];
            hs[v] = make_float4(INV_SQRT2*cnt + 3.0f,
                                INV_SQRT2*SQRT3*(sx - cnt*rx) + SQRT3*ex,
                                INV_SQRT2*SQRT3*(sy - cnt*ry) + SQRT3*ey,
                                INV_SQRT2*SQRT3*(sz - cnt*rz) + SQRT3*ez);
        }
    }
    __syncthreads();

    // ---- phase G2: Mid[v][16] (2 lanes/node) ----------------------------
    {
        int v = t >> 1, ln = t & 1;
        int lo = offs[v], hi = offs[v + 1];
        float rx = rl[v*3+0], ry = rl[v*3+1], rz = rl[v*3+2];
        float A0=0.f, A1=0.f;
        float px=0.f, py=0.f, pz=0.f;
        float qx=0.f, qy=0.f, qz=0.f;
        float cx=0.f, cy=0.f, cz=0.f;
        float t0=0.f, t1=0.f, t2=0.f, t3=0.f, t4=0.f;
        for (int p = lo + ln; p < hi; p += 2) {
            int j = (p < ECAP) ? ec[p] : (edst[gbeg + p] - base);
            float s1x = SQRT3 * (rl[j*3+0] - rx);
            float s1y = SQRT3 * (rl[j*3+1] - ry);
            float s1z = SQRT3 * (rl[j*3+2] - rz);
            float4 a = hs[j];
            float a0 = a.x, a1x = a.y, a1y = a.z, a1z = a.w;
            A0 += a0;
            A1 += a1x*s1x + a1y*s1y + a1z*s1z;
            px += a0*s1x; py += a0*s1y; pz += a0*s1z;
            qx += a1x;    qy += a1y;    qz += a1z;
            cx += a1y*s1z - a1z*s1y;
            cy += a1z*s1x - a1x*s1z;
            cz += a1x*s1y - a1y*s1x;
            t0 += a1x*s1y + a1y*s1x;
            t1 += a1y*s1z + a1z*s1y;
            t2 += 2.0f*a1z*s1z - a1x*s1x - a1y*s1y;
            t3 += a1x*s1z + a1z*s1x;
            t4 += a1x*s1x - a1y*s1y;
        }
#define RED2(v) v += __shfl_xor(v, 1, 2);
        RED2(A0) RED2(A1)
        RED2(px) RED2(py) RED2(pz)
        RED2(qx) RED2(qy) RED2(qz)
        RED2(cx) RED2(cy) RED2(cz)
        RED2(t0) RED2(t1) RED2(t2) RED2(t3) RED2(t4)
#undef RED2
        if (ln == 0) {
            const float kA = INV_SQRT2 * PW1_000;
            const float kB = INV_SQRT2 * K_V0;
            const float kP = INV_SQRT2 * K_P;
            const float kT = INV_SQRT2 * PW1_112 * NC;
            const float kU = INV_SQRT2 * PW1_112 * NC2;
            ml[v*4+0] = make_float4(kA*A0, kB*A1, kP*px, kP*py);
            ml[v*4+1] = make_float4(kP*pz, kP*qx, kP*qy, kP*qz);
            ml[v*4+2] = make_float4(kP*cx, kP*cy, kP*cz, kT*t0);
            ml[v*4+3] = make_float4(kT*t1, kU*t2, kT*t3, kT*t4);
        }
    }
    __syncthreads();

    // ---- phase G3: out[v] (2 lanes/node) ---------------------------------
    {
        int v = t >> 1, ln = t & 1;
        int lo = offs[v], hi = offs[v + 1];
        float rx = rl[v*3+0], ry = rl[v*3+1], rz = rl[v*3+2];
        float D00 = dd[0], D01 = dd[1], D2a = dd[2], D2b = dd[3], D3 = dd[4], D4 = dd[5];
        float ox = 0.f, oy = 0.f, oz = 0.f;
        for (int p = lo + ln; p < hi; p += 2) {
            int j = (p < ECAP) ? ec[p] : (edst[gbeg + p] - base);
            float s1x = SQRT3 * (rl[j*3+0] - rx);
            float s1y = SQRT3 * (rl[j*3+1] - ry);
            float s1z = SQRT3 * (rl[j*3+2] - rz);
            float4 ga = ml[j*4+0], gbv = ml[j*4+1], gc = ml[j*4+2], gd = ml[j*4+3];
            float G0=ga.x,  G1=ga.y,  G2=ga.z,  G3=ga.w;
            float G4=gbv.x, G5=gbv.y, G6=gbv.z, G7=gbv.w;
            float G8=gc.x,  G9=gc.y,  G10=gc.z, G11=gc.w;
            float G12=gd.x, G13=gd.y, G14=gd.z, G15=gd.w;
            // q1
            float q = INV_SQRT3 * (G0*D00 + G1*D01);
            ox += q * s1x; oy += q * s1y; oz += q * s1z;
            // q2
            float c1x = G3*s1z - G4*s1y;
            float c1y = G4*s1x - G2*s1z;
            float c1z = G2*s1y - G3*s1x;
            float c2x = G6*s1z - G7*s1y;
            float c2y = G7*s1x - G5*s1z;
            float c2z = G5*s1y - G6*s1x;
            ox += INV_SQRT6 * (D2a*c1x + D2b*c2x);
            oy += INV_SQRT6 * (D2a*c1y + D2b*c2y);
            oz += INV_SQRT6 * (D2a*c1z + D2b*c2z);
            // q3
            ox += INV_SQRT3 * D3 * G8;
            oy += INV_SQRT3 * D3 * G9;
            oz += INV_SQRT3 * D3 * G10;
            // q4
            ox += D4 * (NC*(s1y*G11 + s1z*G14 + s1x*G15) - NC2*s1x*G13);
            oy += D4 * (NC*(s1x*G11 + s1z*G12 - s1y*G15) - NC2*s1y*G13);
            oz += D4 * (NC*(s1y*G12 + s1x*G14) + 2.0f*NC2*s1z*G13);
        }
        ox += __shfl_xor(ox, 1, 2);
        oy += __shfl_xor(oy, 1, 2);
        oz += __shfl_xor(oz, 1, 2);
        if (ln == 0) {
            out[(base+v)*3+0] = PW2 * INV_SQRT2 * ox;
            out[(base+v)*3+1] = PW2 * INV_SQRT2 * oy;
            out[(base+v)*3+2] = PW2 * INV_SQRT2 * oz;
        }
    }
}

extern "C" void kernel_launch(void* const* d_in, const int* in_sizes, int n_in,
                              void* d_out, int out_size, void* d_ws, size_t ws_size,
                              hipStream_t stream) {
    const int*   nf     = (const int*)  d_in[0];
    const float* rv     = (const float*)d_in[1];
    const int*   esrc   = (const int*)  d_in[2];
    const int*   edst   = (const int*)  d_in[3];
    const float* emb    = (const float*)d_in[4];
    const float* t1_000 = (const float*)d_in[5];
    const float* t1_011 = (const float*)d_in[6];
    const float* t1_101 = (const float*)d_in[7];
    const float* t1_110 = (const float*)d_in[8];
    const float* t1_111 = (const float*)d_in[9];
    const float* t1_112 = (const float*)d_in[10];
    const float* t2_0e  = (const float*)d_in[11];
    const float* t2_1e  = (const float*)d_in[12];
    const float* t2_1o  = (const float*)d_in[13];
    const float* t2_2e  = (const float*)d_in[14];

    const int n     = in_sizes[1] / 3;   // 2048 nodes
    const int E     = in_sizes[2];       // 40960 edge slots
    const int embsz = in_sizes[4];       // 300
    const int nb    = n / NA;            // 4 batches
    float* out = (float*)d_out;

    k_all<<<nb, NTH, 0, stream>>>(
        nf, rv, esrc, edst, emb,
        t1_000, t1_011, t1_101, t1_110, t1_111, t1_112,
        t2_0e, t2_1e, t2_1o, t2_2e,
        out, n, E, embsz);
}

// Round 8
// 26.017 us; speedup vs baseline: 1.6644x; 1.6644x over previous
//
#include <hip/hip_runtime.h>

#define INV_SQRT2 0.70710678118654752f
#define SQRT3     1.73205080756887729f
#define INV_SQRT3 0.57735026918962576f
#define INV_SQRT6 0.40824829046386302f
#define PW1_000   0.70710678118654752f   // sqrt(0.5)
#define PW1_112   2.23606797749978970f   // sqrt(5)
#define K_P       0.70710678118654752f   // PW1_011*INV_SQRT3 = PW1_101*INV_SQRT3 = PW1_111*INV_SQRT6
#define K_V0      0.40824829046386302f   // PW1_110*INV_SQRT3
#define PW2       0.15309310892394863f   // sqrt(3/128)
#define NC        0.31622776601683794f   // 1/sqrt(10)
#define NC2       0.18257418583505537f   // 1/sqrt(30)

#define RED8(v)  { v += __shfl_xor(v,1,8);  v += __shfl_xor(v,2,8);  v += __shfl_xor(v,4,8); }

// lower_bound over monotone key: real edges keep src (globally sorted),
// pads (dst>=n) map to n and sit at the tail.
__device__ __forceinline__ int lbound(const int* __restrict__ esrc,
                                      const int* __restrict__ edst,
                                      int n, int E, int target) {
    int lo = 0, hi = E;
    while (lo < hi) {
        int mid = (lo + hi) >> 1;
        int d = edst[mid];
        int key = (d >= n) ? n : esrc[mid];
        if (key < target) lo = mid + 1; else hi = mid;
    }
    return lo;
}

// ---- prep: weight dots + per-node {offs, Hsum} --------------------------
// Hsum[v] = sum over 4 channels of h[v][c] = h0[v] + [3, sqrt3 * sum emb]
// h0[v] = INV_SQRT2 * [cnt_v, sum_in s1]; in-edges of v = v's out-run reversed.
__global__ void __launch_bounds__(256) k_prep(
    const int* __restrict__ nf, const float* __restrict__ rv,
    const int* __restrict__ esrc, const int* __restrict__ edst,
    const float* __restrict__ emb,
    const float* __restrict__ t1_000, const float* __restrict__ t1_011,
    const float* __restrict__ t1_101, const float* __restrict__ t1_110,
    const float* __restrict__ t1_111, const float* __restrict__ t1_112,
    const float* __restrict__ t2_0e, const float* __restrict__ t2_1e,
    const float* __restrict__ t2_1o, const float* __restrict__ t2_2e,
    float* __restrict__ Dd, float4* __restrict__ Hsum,
    int* __restrict__ offs, int n, int E, int nodeBlocks)
{
    if ((int)blockIdx.x == nodeBlocks) {            // weight-dot block
        int l = threadIdx.x;
        if (l >= 64) return;
        auto wdot = [&](const float* a, const float* b, int len) -> float {
            float v = (l < len) ? a[l] * b[l] : 0.0f;
            for (int off = 32; off > 0; off >>= 1) v += __shfl_down(v, off);
            return v;
        };
        float d0 = wdot(t1_000, t2_0e, 64);
        float d1 = wdot(t1_110, t2_0e, 64);
        float d2 = wdot(t1_011, t2_1e, 24);
        float d3 = wdot(t1_101, t2_1e, 24);
        float d4 = wdot(t1_111, t2_1o, 24);
        float d5 = wdot(t1_112, t2_2e, 16);
        if (l == 0) { Dd[0]=d0; Dd[1]=d1; Dd[2]=d2; Dd[3]=d3; Dd[4]=d4; Dd[5]=d5; }
        return;
    }
    const int tid = blockIdx.x * 256 + threadIdx.x;
    if (tid >= n * 8) return;
    int v = tid >> 3, ln = tid & 7;
    int b = 0;
    if (ln == 0) b = lbound(esrc, edst, n, E, v);
    if (ln == 1) b = lbound(esrc, edst, n, E, v + 1);
    int lo = __shfl(b, 0, 8);
    int hi = __shfl(b, 1, 8);
    float sx = 0.f, sy = 0.f, sz = 0.f;
    for (int p = lo + ln; p < hi; p += 8) {
        int j = edst[p];
        sx += rv[j*3+0]; sy += rv[j*3+1]; sz += rv[j*3+2];
    }
    RED8(sx) RED8(sy) RED8(sz)
    if (ln == 0) {
        float cnt = (float)(hi - lo);
        float rx = rv[v*3+0], ry = rv[v*3+1], rz = rv[v*3+2];
        int i0 = nf[v*3+0], i1 = nf[v*3+1], i2 = nf[v*3+2];
        float ex = emb[i0*3+0] + emb[i1*3+0] + emb[i2*3+0];
        float ey = emb[i0*3+1] + emb[i1*3+1] + emb[i2*3+1];
        float ez = emb[i0*3+2] + emb[i1*3+2] + emb[i2*3+2];
        Hsum[v] = make_float4(INV_SQRT2*cnt + 3.0f,
                              INV_SQRT2*SQRT3*(sx - cnt*rx) + SQRT3*ex,
                              INV_SQRT2*SQRT3*(sy - cnt*ry) + SQRT3*ey,
                              INV_SQRT2*SQRT3*(sz - cnt*rz) + SQRT3*ez);
        offs[v] = lo;
        if (v == n - 1) offs[n] = hi;
    }
}

// ---- out: one wave per node; 2-hop expansion, F applied to partial G ----
// lane = (jslot<<2)|ksub : jslot in [0,16) strides v's run, ksub in [0,4)
// strides j's run. F is linear in Mid so partial-G F-applications sum.
__global__ void __launch_bounds__(256) k_out(
    const float* __restrict__ rv, const int* __restrict__ edst,
    const float4* __restrict__ Hsum, const int* __restrict__ offs,
    const float* __restrict__ Dd, float* __restrict__ out, int n)
{
    const int gid = blockIdx.x * 256 + threadIdx.x;
    const int v = gid >> 6, ln = gid & 63;
    if (v >= n) return;
    const int lo = offs[v], hi = offs[v+1];
    const float rvx = rv[v*3+0], rvy = rv[v*3+1], rvz = rv[v*3+2];
    const float D00 = Dd[0], D01 = Dd[1], D2a = Dd[2], D2b = Dd[3], D3 = Dd[4], D4 = Dd[5];
    const float kA = INV_SQRT2 * PW1_000;
    const float kB = INV_SQRT2 * K_V0;
    const float kP = INV_SQRT2 * K_P;
    const float kT = INV_SQRT2 * PW1_112 * NC;
    const float kU = INV_SQRT2 * PW1_112 * NC2;
    const int jslot = ln >> 2, ksub = ln & 3;
    float ox = 0.f, oy = 0.f, oz = 0.f;

    for (int p = lo + jslot; p < hi; p += 16) {
        int j = edst[p];
        float rjx = rv[j*3+0], rjy = rv[j*3+1], rjz = rv[j*3+2];
        float s1x = SQRT3*(rjx - rvx), s1y = SQRT3*(rjy - rvy), s1z = SQRT3*(rjz - rvz);
        int qlo = offs[j], qhi = offs[j+1];
        // accumulate raw G component sums over this lane's k-subset
        float A0=0.f, A1=0.f;
        float px=0.f, py=0.f, pz=0.f;
        float qx=0.f, qy=0.f, qz=0.f;
        float cx=0.f, cy=0.f, cz=0.f;
        float u0=0.f, u1=0.f, u2=0.f, u3=0.f, u4=0.f;
        for (int q = qlo + ksub; q < qhi; q += 4) {
            int k = edst[q];
            float w1x = SQRT3*(rv[k*3+0] - rjx);
            float w1y = SQRT3*(rv[k*3+1] - rjy);
            float w1z = SQRT3*(rv[k*3+2] - rjz);
            float4 a = Hsum[k];
            float a0 = a.x, a1x = a.y, a1y = a.z, a1z = a.w;
            A0 += a0;
            A1 += a1x*w1x + a1y*w1y + a1z*w1z;
            px += a0*w1x; py += a0*w1y; pz += a0*w1z;
            qx += a1x;    qy += a1y;    qz += a1z;
            cx += a1y*w1z - a1z*w1y;
            cy += a1z*w1x - a1x*w1z;
            cz += a1x*w1y - a1y*w1x;
            u0 += a1x*w1y + a1y*w1x;
            u1 += a1y*w1z + a1z*w1y;
            u2 += 2.0f*a1z*w1z - a1x*w1x - a1y*w1y;
            u3 += a1x*w1z + a1z*w1x;
            u4 += a1x*w1x - a1y*w1y;
        }
        // scale to Mid components
        float G0 = kA*A0, G1 = kB*A1;
        float G2 = kP*px, G3 = kP*py, G4 = kP*pz;
        float G5 = kP*qx, G6 = kP*qy, G7 = kP*qz;
        float G8 = kP*cx, G9 = kP*cy, G10 = kP*cz;
        float G11 = kT*u0, G12 = kT*u1, G13 = kU*u2, G14 = kT*u3, G15 = kT*u4;
        // apply F(s1_vj, G)
        float q1 = INV_SQRT3 * (G0*D00 + G1*D01);
        ox += q1 * s1x; oy += q1 * s1y; oz += q1 * s1z;
        float c1x = G3*s1z - G4*s1y;
        float c1y = G4*s1x - G2*s1z;
        float c1z = G2*s1y - G3*s1x;
        float c2x = G6*s1z - G7*s1y;
        float c2y = G7*s1x - G5*s1z;
        float c2z = G5*s1y - G6*s1x;
        ox += INV_SQRT6 * (D2a*c1x + D2b*c2x);
        oy += INV_SQRT6 * (D2a*c1y + D2b*c2y);
        oz += INV_SQRT6 * (D2a*c1z + D2b*c2z);
        ox += INV_SQRT3 * D3 * G8;
        oy += INV_SQRT3 * D3 * G9;
        oz += INV_SQRT3 * D3 * G10;
        ox += D4 * (NC*(s1y*G11 + s1z*G14 + s1x*G15) - NC2*s1x*G13);
        oy += D4 * (NC*(s1x*G11 + s1z*G12 - s1y*G15) - NC2*s1y*G13);
        oz += D4 * (NC*(s1y*G12 + s1x*G14) + 2.0f*NC2*s1z*G13);
    }
    // full-wave reduction
    for (int m = 1; m < 64; m <<= 1) {
        ox += __shfl_xor(ox, m);
        oy += __shfl_xor(oy, m);
        oz += __shfl_xor(oz, m);
    }
    if (ln == 0) {
        out[v*3+0] = PW2 * INV_SQRT2 * ox;
        out[v*3+1] = PW2 * INV_SQRT2 * oy;
        out[v*3+2] = PW2 * INV_SQRT2 * oz;
    }
}

extern "C" void kernel_launch(void* const* d_in, const int* in_sizes, int n_in,
                              void* d_out, int out_size, void* d_ws, size_t ws_size,
                              hipStream_t stream) {
    const int*   nf     = (const int*)  d_in[0];
    const float* rv     = (const float*)d_in[1];
    const int*   esrc   = (const int*)  d_in[2];
    const int*   edst   = (const int*)  d_in[3];
    const float* emb    = (const float*)d_in[4];
    const float* t1_000 = (const float*)d_in[5];
    const float* t1_011 = (const float*)d_in[6];
    const float* t1_101 = (const float*)d_in[7];
    const float* t1_110 = (const float*)d_in[8];
    const float* t1_111 = (const float*)d_in[9];
    const float* t1_112 = (const float*)d_in[10];
    const float* t2_0e  = (const float*)d_in[11];
    const float* t2_1e  = (const float*)d_in[12];
    const float* t2_1o  = (const float*)d_in[13];
    const float* t2_2e  = (const float*)d_in[14];

    const int n = in_sizes[1] / 3;   // 2048 nodes
    const int E = in_sizes[2];       // 40960 edge slots (real edges + pads)

    // ws layout (all written unconditionally every call; no memset needed):
    // [Hsum n float4][Dd 8 f][offs n+1 int]
    float4* Hsum = (float4*)d_ws;
    float*  Dd   = (float*)(Hsum + n);
    int*    offs = (int*)(Dd + 8);
    float*  out  = (float*)d_out;

    const int nodeBlocks = (n * 8 + 255) / 256;
    k_prep<<<nodeBlocks + 1, 256, 0, stream>>>(
        nf, rv, esrc, edst, emb,
        t1_000, t1_011, t1_101, t1_110, t1_111, t1_112,
        t2_0e, t2_1e, t2_1o, t2_2e,
        Dd, Hsum, offs, n, E, nodeBlocks);
    k_out<<<(n * 64 + 255) / 256, 256, 0, stream>>>(
        rv, edst, Hsum, offs, Dd, out, n);
}

// Round 9
// 18.118 us; speedup vs baseline: 2.3902x; 1.4360x over previous
//
#include <hip/hip_runtime.h>

#define INV_SQRT2 0.70710678118654752f
#define SQRT3     1.73205080756887729f
#define INV_SQRT3 0.57735026918962576f
#define INV_SQRT6 0.40824829046386302f
#define PW1_000   0.70710678118654752f   // sqrt(0.5)
#define PW1_112   2.23606797749978970f   // sqrt(5)
#define K_P       0.70710678118654752f   // PW1_011*INV_SQRT3 = PW1_101*INV_SQRT3 = PW1_111*INV_SQRT6
#define K_V0      0.40824829046386302f   // PW1_110*INV_SQRT3
#define PW2       0.15309310892394863f   // sqrt(3/128)
#define NC        0.31622776601683794f   // 1/sqrt(10)
#define NC2       0.18257418583505537f   // 1/sqrt(30)

#define RED8(v)  { v += __shfl_xor(v,1,8);  v += __shfl_xor(v,2,8);  v += __shfl_xor(v,4,8); }
#define RED16(v) { v += __shfl_xor(v,1,16); v += __shfl_xor(v,2,16); \
                   v += __shfl_xor(v,4,16); v += __shfl_xor(v,8,16); }

#define NS 1280   // coarse sample count (ST = ceil(E/NS) = 32 at E=40960)

// ---- prep: weight dots + per-node {offs, Hsum} --------------------------
// monotone sort key: real edges (dst<n) keep src (globally sorted); pads -> n.
// 2-level lower_bound: coarse over LDS-sampled keys, then <=ST-range refine.
__global__ void __launch_bounds__(256) k_prep(
    const int* __restrict__ nf, const float* __restrict__ rv,
    const int* __restrict__ esrc, const int* __restrict__ edst,
    const float* __restrict__ emb,
    const float* __restrict__ t1_000, const float* __restrict__ t1_011,
    const float* __restrict__ t1_101, const float* __restrict__ t1_110,
    const float* __restrict__ t1_111, const float* __restrict__ t1_112,
    const float* __restrict__ t2_0e, const float* __restrict__ t2_1e,
    const float* __restrict__ t2_1o, const float* __restrict__ t2_2e,
    float* __restrict__ Dd, float4* __restrict__ Hsum,
    int* __restrict__ offs, int n, int E, int nodeBlocks)
{
    if ((int)blockIdx.x == nodeBlocks) {            // weight-dot block
        int l = threadIdx.x;
        if (l >= 64) return;
        auto wdot = [&](const float* a, const float* b, int len) -> float {
            float v = (l < len) ? a[l] * b[l] : 0.0f;
            for (int off = 32; off > 0; off >>= 1) v += __shfl_down(v, off);
            return v;
        };
        float d0 = wdot(t1_000, t2_0e, 64);
        float d1 = wdot(t1_110, t2_0e, 64);
        float d2 = wdot(t1_011, t2_1e, 24);
        float d3 = wdot(t1_101, t2_1e, 24);
        float d4 = wdot(t1_111, t2_1o, 24);
        float d5 = wdot(t1_112, t2_2e, 16);
        if (l == 0) { Dd[0]=d0; Dd[1]=d1; Dd[2]=d2; Dd[3]=d3; Dd[4]=d4; Dd[5]=d5; }
        return;
    }

    __shared__ int ks[NS + 1];
    const int ST = (E + NS - 1) / NS;
    for (int i = threadIdx.x; i <= NS; i += 256) {
        int p = i * ST;
        int key;
        if (p >= E) key = n;
        else { int d = edst[p]; key = (d >= n) ? n : esrc[p]; }
        ks[i] = key;
    }
    __syncthreads();

    const int tid = blockIdx.x * 256 + threadIdx.x;
    if (tid >= n * 8) return;
    int v = tid >> 3, ln = tid & 7;
    int b = 0;
    if (ln < 2) {
        int target = v + ln;
        int lo = 0, hi = NS + 1;                    // coarse over ks (LDS)
        while (lo < hi) { int m = (lo + hi) >> 1; if (ks[m] < target) lo = m + 1; else hi = m; }
        int glo = (lo == 0) ? 0 : (lo - 1) * ST;
        int ghi = lo * ST; if (ghi > E) ghi = E;
        while (glo < ghi) {                         // refine in global (<=5 steps)
            int m = (glo + ghi) >> 1;
            int d = edst[m];
            int k = (d >= n) ? n : esrc[m];
            if (k < target) glo = m + 1; else ghi = m;
        }
        b = glo;
    }
    int lo = __shfl(b, 0, 8);
    int hi = __shfl(b, 1, 8);
    float sx = 0.f, sy = 0.f, sz = 0.f;
    for (int p = lo + ln; p < hi; p += 8) {
        int j = edst[p];
        sx += rv[j*3+0]; sy += rv[j*3+1]; sz += rv[j*3+2];
    }
    RED8(sx) RED8(sy) RED8(sz)
    if (ln == 0) {
        float cnt = (float)(hi - lo);
        float rx = rv[v*3+0], ry = rv[v*3+1], rz = rv[v*3+2];
        int i0 = nf[v*3+0], i1 = nf[v*3+1], i2 = nf[v*3+2];
        float ex = emb[i0*3+0] + emb[i1*3+0] + emb[i2*3+0];
        float ey = emb[i0*3+1] + emb[i1*3+1] + emb[i2*3+1];
        float ez = emb[i0*3+2] + emb[i1*3+2] + emb[i2*3+2];
        Hsum[v] = make_float4(INV_SQRT2*cnt + 3.0f,
                              INV_SQRT2*SQRT3*(sx - cnt*rx) + SQRT3*ex,
                              INV_SQRT2*SQRT3*(sy - cnt*ry) + SQRT3*ey,
                              INV_SQRT2*SQRT3*(sz - cnt*rz) + SQRT3*ez);
        offs[v] = lo;
        if (v == n - 1) offs[n] = hi;
    }
}

// ---- gather 2: channel-presummed Mid[v][16]; 16 lanes/node -------------
__global__ void __launch_bounds__(256) k_g2(
    const float* __restrict__ rv, const int* __restrict__ edst,
    const int* __restrict__ offs, const float4* __restrict__ Hsum,
    float* __restrict__ Mid, int n)
{
    int tid = blockIdx.x * blockDim.x + threadIdx.x;
    if (tid >= n * 16) return;
    int v = tid >> 4, ln = tid & 15;
    int lo = offs[v], hi = offs[v+1];
    float rvx = rv[v*3+0], rvy = rv[v*3+1], rvz = rv[v*3+2];
    float A0=0.f, A1=0.f;
    float px=0.f, py=0.f, pz=0.f;
    float qx=0.f, qy=0.f, qz=0.f;
    float cx=0.f, cy=0.f, cz=0.f;
    float t0=0.f, t1=0.f, t2=0.f, t3=0.f, t4=0.f;
    for (int p = lo + ln; p < hi; p += 16) {
        int j = edst[p];
        float s1x = SQRT3*(rv[j*3+0] - rvx);
        float s1y = SQRT3*(rv[j*3+1] - rvy);
        float s1z = SQRT3*(rv[j*3+2] - rvz);
        float4 a = Hsum[j];
        float a0 = a.x, a1x = a.y, a1y = a.z, a1z = a.w;
        A0 += a0;
        A1 += a1x*s1x + a1y*s1y + a1z*s1z;
        px += a0*s1x; py += a0*s1y; pz += a0*s1z;
        qx += a1x;    qy += a1y;    qz += a1z;
        cx += a1y*s1z - a1z*s1y;
        cy += a1z*s1x - a1x*s1z;
        cz += a1x*s1y - a1y*s1x;
        t0 += a1x*s1y + a1y*s1x;
        t1 += a1y*s1z + a1z*s1y;
        t2 += 2.0f*a1z*s1z - a1x*s1x - a1y*s1y;
        t3 += a1x*s1z + a1z*s1x;
        t4 += a1x*s1x - a1y*s1y;
    }
    RED16(A0) RED16(A1)
    RED16(px) RED16(py) RED16(pz)
    RED16(qx) RED16(qy) RED16(qz)
    RED16(cx) RED16(cy) RED16(cz)
    RED16(t0) RED16(t1) RED16(t2) RED16(t3) RED16(t4)
    if (ln == 0) {
        const float kA = INV_SQRT2 * PW1_000;
        const float kB = INV_SQRT2 * K_V0;
        const float kP = INV_SQRT2 * K_P;
        const float kT = INV_SQRT2 * PW1_112 * NC;
        const float kU = INV_SQRT2 * PW1_112 * NC2;
        float4* md = (float4*)(Mid + v*16);
        md[0] = make_float4(kA*A0, kB*A1, kP*px, kP*py);
        md[1] = make_float4(kP*pz, kP*qx, kP*qy, kP*qz);
        md[2] = make_float4(kP*cx, kP*cy, kP*cz, kT*t0);
        md[3] = make_float4(kT*t1, kU*t2, kT*t3, kT*t4);
    }
}

// ---- gather 3: out[v]; 16 lanes/node -----------------------------------
__global__ void __launch_bounds__(256) k_g3(
    const float* __restrict__ rv, const int* __restrict__ edst,
    const int* __restrict__ offs, const float* __restrict__ Mid,
    const float* __restrict__ Dd, float* __restrict__ out, int n)
{
    int tid = blockIdx.x * blockDim.x + threadIdx.x;
    if (tid >= n * 16) return;
    int v = tid >> 4, ln = tid & 15;
    int lo = offs[v], hi = offs[v+1];
    float rvx = rv[v*3+0], rvy = rv[v*3+1], rvz = rv[v*3+2];
    float D00 = Dd[0], D01 = Dd[1], D2a = Dd[2], D2b = Dd[3], D3 = Dd[4], D4 = Dd[5];
    float ox = 0.f, oy = 0.f, oz = 0.f;
    for (int p = lo + ln; p < hi; p += 16) {
        int j = edst[p];
        float s1x = SQRT3*(rv[j*3+0] - rvx);
        float s1y = SQRT3*(rv[j*3+1] - rvy);
        float s1z = SQRT3*(rv[j*3+2] - rvz);
        const float4* m4 = (const float4*)(Mid + j*16);
        float4 ga = m4[0], gb = m4[1], gc = m4[2], gd = m4[3];
        float G0=ga.x, G1=ga.y, G2=ga.z, G3=ga.w;
        float G4=gb.x, G5=gb.y, G6=gb.z, G7=gb.w;
        float G8=gc.x, G9=gc.y, G10=gc.z, G11=gc.w;
        float G12=gd.x, G13=gd.y, G14=gd.z, G15=gd.w;
        // q1
        float q = INV_SQRT3 * (G0*D00 + G1*D01);
        ox += q * s1x; oy += q * s1y; oz += q * s1z;
        // q2
        float c1x = G3*s1z - G4*s1y;
        float c1y = G4*s1x - G2*s1z;
        float c1z = G2*s1y - G3*s1x;
        float c2x = G6*s1z - G7*s1y;
        float c2y = G7*s1x - G5*s1z;
        float c2z = G5*s1y - G6*s1x;
        ox += INV_SQRT6 * (D2a*c1x + D2b*c2x);
        oy += INV_SQRT6 * (D2a*c1y + D2b*c2y);
        oz += INV_SQRT6 * (D2a*c1z + D2b*c2z);
        // q3
        ox += INV_SQRT3 * D3 * G8;
        oy += INV_SQRT3 * D3 * G9;
        oz += INV_SQRT3 * D3 * G10;
        // q4
        ox += D4 * (NC*(s1y*G11 + s1z*G14 + s1x*G15) - NC2*s1x*G13);
        oy += D4 * (NC*(s1x*G11 + s1z*G12 - s1y*G15) - NC2*s1y*G13);
        oz += D4 * (NC*(s1y*G12 + s1x*G14) + 2.0f*NC2*s1z*G13);
    }
    RED16(ox) RED16(oy) RED16(oz)
    if (ln == 0) {
        out[v*3+0] = PW2 * INV_SQRT2 * ox;
        out[v*3+1] = PW2 * INV_SQRT2 * oy;
        out[v*3+2] = PW2 * INV_SQRT2 * oz;
    }
}

extern "C" void kernel_launch(void* const* d_in, const int* in_sizes, int n_in,
                              void* d_out, int out_size, void* d_ws, size_t ws_size,
                              hipStream_t stream) {
    const int*   nf     = (const int*)  d_in[0];
    const float* rv     = (const float*)d_in[1];
    const int*   esrc   = (const int*)  d_in[2];
    const int*   edst   = (const int*)  d_in[3];
    const float* emb    = (const float*)d_in[4];
    const float* t1_000 = (const float*)d_in[5];
    const float* t1_011 = (const float*)d_in[6];
    const float* t1_101 = (const float*)d_in[7];
    const float* t1_110 = (const float*)d_in[8];
    const float* t1_111 = (const float*)d_in[9];
    const float* t1_112 = (const float*)d_in[10];
    const float* t2_0e  = (const float*)d_in[11];
    const float* t2_1e  = (const float*)d_in[12];
    const float* t2_1o  = (const float*)d_in[13];
    const float* t2_2e  = (const float*)d_in[14];

    const int n = in_sizes[1] / 3;   // 2048 nodes
    const int E = in_sizes[2];       // 40960 edge slots (real edges + pads)

    // ws layout (all written unconditionally every call; no memset needed):
    // [Hsum n float4][Mid n*16 f][Dd 8 f][offs n+1 int]
    float4* Hsum = (float4*)d_ws;
    float*  Mid  = (float*)(Hsum + n);
    float*  Dd   = Mid + (size_t)n * 16;
    int*    offs = (int*)(Dd + 8);
    float*  out  = (float*)d_out;

    const int nodeBlocks = (n * 8 + 255) / 256;
    k_prep<<<nodeBlocks + 1, 256, 0, stream>>>(
        nf, rv, esrc, edst, emb,
        t1_000, t1_011, t1_101, t1_110, t1_111, t1_112,
        t2_0e, t2_1e, t2_1o, t2_2e,
        Dd, Hsum, offs, n, E, nodeBlocks);
    k_g2<<<(n * 16 + 255) / 256, 256, 0, stream>>>(rv, edst, offs, Hsum, Mid, n);
    k_g3<<<(n * 16 + 255) / 256, 256, 0, stream>>>(rv, edst, offs, Mid, Dd, out, n);
}